// Round 4
// baseline (590.987 us; speedup 1.0000x reference)
//
#include <hip/hip_runtime.h>
#include <hip/hip_bf16.h>
#include <stdint.h>
#include <math.h>

#define SEQ 2048
#define NTOK 8192        // B*S
#define EMB 1024
#define NH 16
#define HD 64
#define FFD 4096

using us = unsigned short;
using b8 = __attribute__((ext_vector_type(8))) __bf16;
using f4 = __attribute__((ext_vector_type(4))) float;

__device__ __forceinline__ us f2b(float f) {
  union { float f; uint32_t u; } v; v.f = f;
  uint32_t u = v.u;
  return (us)((u + 0x7fffu + ((u >> 16) & 1u)) >> 16);  // RNE
}

// pack two fp32 -> bf16x2 (round-half-up; P in [0,1], bias negligible)
__device__ __forceinline__ uint32_t pkbf(float a, float b) {
  union { float f; uint32_t u; } x, y; x.f = a; y.f = b;
  return ((x.u + 0x8000u) >> 16) | ((y.u + 0x8000u) & 0xFFFF0000u);
}

__device__ __forceinline__ void async16(void* lds, const void* g) {
  __builtin_amdgcn_global_load_lds(
      (__attribute__((address_space(1))) void*)(uintptr_t)g,
      (__attribute__((address_space(3))) void*)(uintptr_t)lds, 16, 0, 0);
}

// ---------------- transpose + cast: in [R][C] f32 -> out [C][R] bf16 ----------------
__global__ __launch_bounds__(256)
void transpose_cast(const float* __restrict__ in, us* __restrict__ out, int R, int C) {
  __shared__ float tile[32][33];
  const int bc = blockIdx.x * 32, br = blockIdx.y * 32;
  const int tx = threadIdx.x & 31, ty = threadIdx.x >> 5;
#pragma unroll
  for (int i = 0; i < 32; i += 8)
    tile[ty + i][tx] = in[(size_t)(br + ty + i) * C + bc + tx];
  __syncthreads();
#pragma unroll
  for (int i = 0; i < 32; i += 8)
    out[(size_t)(bc + ty + i) * R + br + tx] = f2b(tile[tx][ty + i]);
}

// ---------------- pack bq|bk|bv into one [3072] ----------------
__global__ void pack_bias(const float* __restrict__ bq, const float* __restrict__ bk,
                          const float* __restrict__ bv, float* __restrict__ o) {
  int i = blockIdx.x * 256 + threadIdx.x;
  o[i] = (i < 1024) ? bq[i] : (i < 2048 ? bk[i - 1024] : bv[i - 2048]);
}

// ---------------- LayerNorm: fp32 in -> bf16 out, one block per token ----------------
__global__ __launch_bounds__(256)
void ln_kernel(const float* __restrict__ x, const float* __restrict__ g,
               const float* __restrict__ be, us* __restrict__ out) {
  __shared__ float red[8];
  const int row = blockIdx.x, t = threadIdx.x;
  const float4 v = ((const float4*)(x + (size_t)row * EMB))[t];
  float s = v.x + v.y + v.z + v.w;
  float s2 = v.x * v.x + v.y * v.y + v.z * v.z + v.w * v.w;
#pragma unroll
  for (int o = 32; o; o >>= 1) { s += __shfl_down(s, o, 64); s2 += __shfl_down(s2, o, 64); }
  if ((t & 63) == 0) { red[(t >> 6) * 2] = s; red[(t >> 6) * 2 + 1] = s2; }
  __syncthreads();
  const float ts = red[0] + red[2] + red[4] + red[6];
  const float ts2 = red[1] + red[3] + red[5] + red[7];
  const float mu = ts * (1.f / 1024.f);
  const float rs = rsqrtf(ts2 * (1.f / 1024.f) - mu * mu + 1e-5f);
  const float4 gv = ((const float4*)g)[t];
  const float4 bv = ((const float4*)be)[t];
  ushort4 o4;
  o4.x = f2b((v.x - mu) * rs * gv.x + bv.x);
  o4.y = f2b((v.y - mu) * rs * gv.y + bv.y);
  o4.z = f2b((v.z - mu) * rs * gv.z + bv.z);
  o4.w = f2b((v.w - mu) * rs * gv.w + bv.w);
  ((ushort4*)(out + (size_t)row * EMB))[t] = o4;
}

// ---------------- GEMM 128x128: C[M][N] = epi(A[M][K] @ Bt[N][K]^T + bias) ----------------
// BK=32, 4 waves (2x2), 16x16x32 bf16 MFMA, global_load_lds staging,
// XOR col-swizzle (phys_col8 = col8 ^ (row&3)) -> 2-way-max LDS reads.
__global__ __launch_bounds__(256, 2)
void gemm_bt(const us* __restrict__ A, const us* __restrict__ Bt,
             const float* __restrict__ bias, const float* __restrict__ resid,
             float* __restrict__ outF, us* __restrict__ outB,
             int M, int N, int K, int gelu) {
  __shared__ us As[128 * 32];
  __shared__ us Bs[128 * 32];
  const int tid = threadIdx.x;
  const int wave = tid >> 6, lane = tid & 63;
  const int wm = wave & 1, wn = wave >> 1;
  const int quad = lane >> 4, l15 = lane & 15;
  const int row0 = blockIdx.x * 128, col0 = blockIdx.y * 128;

  const f4 zf = {0.f, 0.f, 0.f, 0.f};
  f4 acc[4][4];
#pragma unroll
  for (int i = 0; i < 4; i++)
#pragma unroll
    for (int j = 0; j < 4; j++) acc[i][j] = zf;

  const int srow = lane >> 2;                       // staged row within 16-row op
  const int scol = ((lane & 3) ^ (srow & 3)) * 8;   // swizzled source col (us)
  const us* Ap = A + (size_t)(row0 + wave * 32 + srow) * K + scol;
  const us* Bp = Bt + (size_t)(col0 + wave * 32 + srow) * K + scol;
  us* as0 = &As[(wave * 32) * 32];
  us* as1 = &As[(wave * 32 + 16) * 32];
  us* bs0 = &Bs[(wave * 32) * 32];
  us* bs1 = &Bs[(wave * 32 + 16) * 32];
  const size_t rstep = (size_t)16 * K;
  const int rc = (quad ^ (l15 & 3)) << 3;           // phys col8 offset for reads

  for (int k0 = 0; k0 < K; k0 += 32) {
    async16(as0, Ap + k0);
    async16(as1, Ap + rstep + k0);
    async16(bs0, Bp + k0);
    async16(bs1, Bp + rstep + k0);
    __syncthreads();   // drains vmcnt for global_load_lds
    b8 af[4], bf[4];
#pragma unroll
    for (int i = 0; i < 4; i++) {
      af[i] = *(const b8*)&As[(wm * 64 + i * 16 + l15) * 32 + rc];
      bf[i] = *(const b8*)&Bs[(wn * 64 + i * 16 + l15) * 32 + rc];
    }
#pragma unroll
    for (int i = 0; i < 4; i++)
#pragma unroll
      for (int j = 0; j < 4; j++)
        acc[i][j] = __builtin_amdgcn_mfma_f32_16x16x32_bf16(af[i], bf[j], acc[i][j], 0, 0, 0);
    __syncthreads();
  }

  float bcol[4];
#pragma unroll
  for (int j = 0; j < 4; j++) bcol[j] = bias[col0 + wn * 64 + j * 16 + l15];
#pragma unroll
  for (int i = 0; i < 4; i++)
#pragma unroll
    for (int j = 0; j < 4; j++)
#pragma unroll
      for (int r = 0; r < 4; r++) {
        const int grow = row0 + wm * 64 + i * 16 + quad * 4 + r;
        const int gcol = col0 + wn * 64 + j * 16 + l15;
        float v = acc[i][j][r] + bcol[j];
        if (resid) v += resid[(size_t)grow * N + gcol];
        if (gelu) v = 0.5f * v * (1.f + erff(v * 0.70710678118654752f));
        if (outF) outF[(size_t)grow * N + gcol] = v;
        if (outB) outB[(size_t)grow * N + gcol] = f2b(v);
      }
}

// ---------------- GEMM 64x128 (narrow-N variant, doubles grid for N=1024) ----------------
// 4 waves, each computes the full 64 rows x its 32-col strip. 12 KB LDS.
__global__ __launch_bounds__(256, 4)
void gemm_bt64(const us* __restrict__ A, const us* __restrict__ Bt,
               const float* __restrict__ bias, const float* __restrict__ resid,
               float* __restrict__ outF, us* __restrict__ outB,
               int M, int N, int K, int gelu) {
  __shared__ us As[64 * 32];
  __shared__ us Bs[128 * 32];
  const int tid = threadIdx.x;
  const int wave = tid >> 6, lane = tid & 63;
  const int quad = lane >> 4, l15 = lane & 15;
  const int row0 = blockIdx.x * 64, col0 = blockIdx.y * 128;

  const f4 zf = {0.f, 0.f, 0.f, 0.f};
  f4 acc[4][2];
#pragma unroll
  for (int i = 0; i < 4; i++) { acc[i][0] = zf; acc[i][1] = zf; }

  const int srow = lane >> 2;
  const int scol = ((lane & 3) ^ (srow & 3)) * 8;
  const us* Ap = A + (size_t)(row0 + wave * 16 + srow) * K + scol;   // 1 op: rows wave*16..+15
  const us* Bp = Bt + (size_t)(col0 + wave * 32 + srow) * K + scol;  // 2 ops: rows wave*32..+31
  us* asd = &As[(wave * 16) * 32];
  us* bs0 = &Bs[(wave * 32) * 32];
  us* bs1 = &Bs[(wave * 32 + 16) * 32];
  const size_t rstep = (size_t)16 * K;
  const int rc = (quad ^ (l15 & 3)) << 3;

  for (int k0 = 0; k0 < K; k0 += 32) {
    async16(asd, Ap + k0);
    async16(bs0, Bp + k0);
    async16(bs1, Bp + rstep + k0);
    __syncthreads();
    b8 af[4], bf[2];
#pragma unroll
    for (int i = 0; i < 4; i++)
      af[i] = *(const b8*)&As[(i * 16 + l15) * 32 + rc];
#pragma unroll
    for (int j = 0; j < 2; j++)
      bf[j] = *(const b8*)&Bs[(wave * 32 + j * 16 + l15) * 32 + rc];
#pragma unroll
    for (int i = 0; i < 4; i++)
#pragma unroll
      for (int j = 0; j < 2; j++)
        acc[i][j] = __builtin_amdgcn_mfma_f32_16x16x32_bf16(af[i], bf[j], acc[i][j], 0, 0, 0);
    __syncthreads();
  }

  float bcol[2];
#pragma unroll
  for (int j = 0; j < 2; j++) bcol[j] = bias[col0 + wave * 32 + j * 16 + l15];
#pragma unroll
  for (int i = 0; i < 4; i++)
#pragma unroll
    for (int j = 0; j < 2; j++)
#pragma unroll
      for (int r = 0; r < 4; r++) {
        const int grow = row0 + i * 16 + quad * 4 + r;
        const int gcol = col0 + wave * 32 + j * 16 + l15;
        float v = acc[i][j][r] + bcol[j];
        if (resid) v += resid[(size_t)grow * N + gcol];
        if (gelu) v = 0.5f * v * (1.f + erff(v * 0.70710678118654752f));
        if (outF) outF[(size_t)grow * N + gcol] = v;
        if (outB) outB[(size_t)grow * N + gcol] = f2b(v);
      }
}

// ---------------- causal flash attention, operand-swapped, reg-blocked ----------------
// qkv: [NTOK][3072] bf16 (q|k|v). y: [NTOK][1024] bf16.
// S^T = K·Q^T (P stays in registers in A-layout for O = P·V).
// 256 threads = 4 waves; each wave owns 32 q-rows (two 16-q groups) of a 128-q tile.
// K in LDS with XOR column swizzle (conflict-free b128 reads, async-DMA staged).
// V^T in LDS stride 132 us, b64 reads + register zero-pad (conflict-free).
__global__ __launch_bounds__(256, 3)
void attn(const us* __restrict__ qkv, us* __restrict__ y) {
  // magic-square qt mapping: each CU-coset of blocks gets equal total work
  static const signed char QTM[16] = {15,14,13,12, 10,11,8,9, 5,4,7,6, 0,1,2,3};
  const int bx = blockIdx.x;
  const int bh = bx & 63;
  const int qt = QTM[(bx >> 6) & 15];
  const int bb = bh >> 4, h = bh & 15;
  const int tid = threadIdx.x;
  const int wave = tid >> 6, lane = tid & 63;
  const int quad = lane >> 4, l15 = lane & 15;

  __shared__ us Ks[128 * 64];   // phys us off = row*64 + ((col8 ^ (row&7))<<3)
  __shared__ us Vt[64 * 132];   // V^T[d][key], us off = d*132 + key

  const size_t base = (size_t)bb * SEQ * 3072;
  const int q0 = qt * 128;

  // Q B-fragments for two 16-q groups (rows wave*32 + qg*16 + l15)
  b8 bqf[2][2];
#pragma unroll
  for (int qg = 0; qg < 2; qg++) {
    const us* qp = qkv + base + (size_t)(q0 + wave * 32 + qg * 16 + l15) * 3072 + h * 64 + quad * 8;
    bqf[qg][0] = *(const b8*)qp;
    bqf[qg][1] = *(const b8*)(qp + 32);
  }

  const f4 zf = {0.f, 0.f, 0.f, 0.f};
  f4 o[2][4];                       // [qg][dg]: O[q=quad*4+r][d=dg*16+l15]
  float mrow[2], lrow[2];
#pragma unroll
  for (int qg = 0; qg < 2; qg++) {
    mrow[qg] = -3.0e38f; lrow[qg] = 0.f;
#pragma unroll
    for (int dg = 0; dg < 4; dg++) o[qg][dg] = zf;
  }

  // K staging: wave stages rows wave*32..+31 in 4 DMA ops of 8 rows.
  const int klr = lane >> 3, klc = lane & 7;
  const us* kgbase = qkv + base + (size_t)(wave * 32 + klr) * 3072 + 1024 + h * 64 + ((klc ^ klr) << 3);
  // V staging: thread handles key pair (2*lane, 2*lane+1), d-octets wave*8 and 32+wave*8.
  const us* vgbase = qkv + base + (size_t)(2 * lane) * 3072 + 2048 + h * 64 + wave * 8;

  const float sm_scale = 0.125f * 1.44269504088896340736f;  // 1/sqrt(64) * log2(e)

  for (int kt = 0; kt <= qt; kt++) {
    const size_t koff = (size_t)kt * 128 * 3072;
    // --- stage K (async DMA, XOR-swizzled source) ---
#pragma unroll
    for (int op = 0; op < 4; op++)
      async16(&Ks[(wave * 32 + op * 8) * 64], kgbase + koff + (size_t)op * 8 * 3072);
    // --- stage V^T (manual transpose, conflict-free packed writes) ---
    {
      union { float4 f; us u[8]; } v0, v1, v2, v3;
      v0.f = *(const float4*)(vgbase + koff);
      v1.f = *(const float4*)(vgbase + koff + 3072);
      v2.f = *(const float4*)(vgbase + koff + 32);
      v3.f = *(const float4*)(vgbase + koff + 3072 + 32);
#pragma unroll
      for (int j = 0; j < 8; j++) {
        *(uint32_t*)&Vt[(wave * 8 + j) * 132 + 2 * lane] =
            (uint32_t)v0.u[j] | ((uint32_t)v1.u[j] << 16);
        *(uint32_t*)&Vt[(32 + wave * 8 + j) * 132 + 2 * lane] =
            (uint32_t)v2.u[j] | ((uint32_t)v3.u[j] << 16);
      }
    }
    __syncthreads();

    // --- S^T = K·Q^T : sacc[qg][c] holds S^T[key=c*16+quad*4+r][q=l15] ---
    f4 sacc[2][8];
#pragma unroll
    for (int c = 0; c < 8; c++) {
      const int krow = (c * 16 + l15) * 64;
      const int sw = l15 & 7;
      const b8 ak0 = *(const b8*)&Ks[krow + ((quad ^ sw) << 3)];
      const b8 ak1 = *(const b8*)&Ks[krow + (((quad ^ 4) ^ sw) << 3)];
#pragma unroll
      for (int qg = 0; qg < 2; qg++) {
        f4 s = __builtin_amdgcn_mfma_f32_16x16x32_bf16(ak0, bqf[qg][0], zf, 0, 0, 0);
        sacc[qg][c] = __builtin_amdgcn_mfma_f32_16x16x32_bf16(ak1, bqf[qg][1], s, 0, 0, 0);
      }
    }

    // --- softmax per q-group; pack P into A-fragment halves ---
    uint32_t pf[2][16];
    float alpha[2];
#pragma unroll
    for (int qg = 0; qg < 2; qg++) {
      const int q_in = wave * 32 + qg * 16 + l15;
#pragma unroll
      for (int c = 0; c < 8; c++)
#pragma unroll
        for (int r = 0; r < 4; r++) {
          float v = sacc[qg][c][r] * sm_scale;
          if (kt == qt && (c * 16 + quad * 4 + r) > q_in) v = -3.0e38f;
          sacc[qg][c][r] = v;
        }
      float mx = sacc[qg][0][0];
#pragma unroll
      for (int c = 0; c < 8; c++)
#pragma unroll
        for (int r = 0; r < 4; r++) mx = fmaxf(mx, sacc[qg][c][r]);
      mx = fmaxf(mx, __shfl_xor(mx, 16, 64));
      mx = fmaxf(mx, __shfl_xor(mx, 32, 64));
      const float mnew = fmaxf(mrow[qg], mx);
      alpha[qg] = __builtin_amdgcn_exp2f(mrow[qg] - mnew);
      mrow[qg] = mnew;
      float rs = 0.f;
#pragma unroll
      for (int c = 0; c < 8; c++) {
        const float p0 = __builtin_amdgcn_exp2f(sacc[qg][c][0] - mnew);
        const float p1 = __builtin_amdgcn_exp2f(sacc[qg][c][1] - mnew);
        const float p2 = __builtin_amdgcn_exp2f(sacc[qg][c][2] - mnew);
        const float p3 = __builtin_amdgcn_exp2f(sacc[qg][c][3] - mnew);
        rs += (p0 + p1) + (p2 + p3);
        pf[qg][c * 2] = pkbf(p0, p1);
        pf[qg][c * 2 + 1] = pkbf(p2, p3);
      }
      rs += __shfl_xor(rs, 16, 64);
      rs += __shfl_xor(rs, 32, 64);
      lrow[qg] = lrow[qg] * alpha[qg] + rs;
      // rescale O rows (row q' = quad*4+r needs alpha from lane l15=q')
#pragma unroll
      for (int r = 0; r < 4; r++) {
        const float ar = __shfl(alpha[qg], quad * 4 + r, 64);
#pragma unroll
        for (int dg = 0; dg < 4; dg++) o[qg][dg][r] *= ar;
      }
    }

    // --- O += P·V : V b64 reads shared across q-groups; zero-padded halves ---
#pragma unroll
    for (int c = 0; c < 8; c++) {
      union { uint32_t w[4]; b8 v; } af0, af1;
      af0.w[0] = pf[0][c * 2]; af0.w[1] = pf[0][c * 2 + 1]; af0.w[2] = 0u; af0.w[3] = 0u;
      af1.w[0] = pf[1][c * 2]; af1.w[1] = pf[1][c * 2 + 1]; af1.w[2] = 0u; af1.w[3] = 0u;
#pragma unroll
      for (int dg = 0; dg < 4; dg++) {
        const uint2 vd = *(const uint2*)&Vt[(dg * 16 + l15) * 132 + c * 16 + quad * 4];
        union { uint32_t w[4]; b8 v; } vb;
        vb.w[0] = vd.x; vb.w[1] = vd.y; vb.w[2] = 0u; vb.w[3] = 0u;
        o[0][dg] = __builtin_amdgcn_mfma_f32_16x16x32_bf16(af0.v, vb.v, o[0][dg], 0, 0, 0);
        o[1][dg] = __builtin_amdgcn_mfma_f32_16x16x32_bf16(af1.v, vb.v, o[1][dg], 0, 0, 0);
      }
    }
    __syncthreads();   // before next tile overwrites Ks/Vt
  }

#pragma unroll
  for (int qg = 0; qg < 2; qg++) {
    float lr[4];
#pragma unroll
    for (int r = 0; r < 4; r++) lr[r] = __shfl(lrow[qg], quad * 4 + r, 64);
#pragma unroll
    for (int dg = 0; dg < 4; dg++)
#pragma unroll
      for (int r = 0; r < 4; r++) {
        const int gq = q0 + wave * 32 + qg * 16 + quad * 4 + r;
        y[(size_t)(bb * SEQ + gq) * EMB + h * 64 + dg * 16 + l15] = f2b(o[qg][dg][r] / lr[r]);
      }
  }
}

extern "C" void kernel_launch(void* const* d_in, const int* in_sizes, int n_in,
                              void* d_out, int out_size, void* d_ws, size_t ws_size,
                              hipStream_t stream) {
  const float* x = (const float*)d_in[0];
  const float* Wq = (const float*)d_in[1];
  const float* bq = (const float*)d_in[2];
  const float* Wk = (const float*)d_in[3];
  const float* bk = (const float*)d_in[4];
  const float* Wv = (const float*)d_in[5];
  const float* bv = (const float*)d_in[6];
  const float* Wo = (const float*)d_in[7];
  const float* bo = (const float*)d_in[8];
  const float* g1 = (const float*)d_in[9];
  const float* be1 = (const float*)d_in[10];
  const float* g2 = (const float*)d_in[11];
  const float* be2 = (const float*)d_in[12];
  const float* W1 = (const float*)d_in[13];
  const float* b1 = (const float*)d_in[14];
  const float* W2 = (const float*)d_in[15];
  const float* b2 = (const float*)d_in[16];
  float* out = (float*)d_out;

  char* ws = (char*)d_ws;
  const size_t MB = 1024ull * 1024ull;
  us* WqkvT = (us*)(ws + 0);          // [3072][1024] bf16
  us* WoT   = (us*)(ws + 6 * MB);     // [1024][1024]
  us* W1T   = (us*)(ws + 8 * MB);     // [4096][1024]
  us* W2T   = (us*)(ws + 16 * MB);    // [1024][4096]
  us* hbuf  = (us*)(ws + 24 * MB);    // [8192][1024] bf16 (LN1 out)
  us* qkvb  = (us*)(ws + 40 * MB);    // [8192][3072] bf16
  us* ybuf  = (us*)(ws + 88 * MB);    // [8192][1024] bf16
  float* x1 = (float*)(ws + 104 * MB);// [8192][1024] f32
  us* h2    = (us*)(ws + 136 * MB);   // [8192][1024] bf16
  us* ff1   = (us*)(ws + 24 * MB);    // [8192][4096] bf16 (reuses h/qkv region)
  float* bqkv = (float*)(ws + 152 * MB); // [3072] f32

  transpose_cast<<<dim3(32, 32), 256, 0, stream>>>(Wq, WqkvT, 1024, 1024);
  transpose_cast<<<dim3(32, 32), 256, 0, stream>>>(Wk, WqkvT + 1024 * 1024, 1024, 1024);
  transpose_cast<<<dim3(32, 32), 256, 0, stream>>>(Wv, WqkvT + 2 * 1024 * 1024, 1024, 1024);
  transpose_cast<<<dim3(32, 32), 256, 0, stream>>>(Wo, WoT, 1024, 1024);
  transpose_cast<<<dim3(128, 32), 256, 0, stream>>>(W1, W1T, 1024, 4096);
  transpose_cast<<<dim3(32, 128), 256, 0, stream>>>(W2, W2T, 4096, 1024);
  pack_bias<<<12, 256, 0, stream>>>(bq, bk, bv, bqkv);

  ln_kernel<<<NTOK, 256, 0, stream>>>(x, g1, be1, hbuf);
  gemm_bt<<<dim3(64, 24), 256, 0, stream>>>(hbuf, WqkvT, bqkv, nullptr, nullptr, qkvb,
                                            NTOK, 3072, 1024, 0);
  attn<<<1024, 256, 0, stream>>>(qkvb, ybuf);
  gemm_bt64<<<dim3(128, 8), 256, 0, stream>>>(ybuf, WoT, bo, x, x1, nullptr,
                                              NTOK, 1024, 1024, 0);
  ln_kernel<<<NTOK, 256, 0, stream>>>(x1, g2, be2, h2);
  gemm_bt<<<dim3(64, 32), 256, 0, stream>>>(h2, W1T, b1, nullptr, nullptr, ff1,
                                            NTOK, 4096, 1024, 1);
  gemm_bt64<<<dim3(128, 8), 256, 0, stream>>>(ff1, W2T, b2, x1, out, nullptr,
                                              NTOK, 1024, 4096, 0);
}

// Round 5
// 562.854 us; speedup vs baseline: 1.0500x; 1.0500x over previous
//
#include <hip/hip_runtime.h>
#include <hip/hip_bf16.h>
#include <stdint.h>
#include <math.h>

#define SEQ 2048
#define NTOK 8192        // B*S
#define EMB 1024
#define NH 16
#define HD 64
#define FFD 4096

using us = unsigned short;
using b8 = __attribute__((ext_vector_type(8))) __bf16;
using f4 = __attribute__((ext_vector_type(4))) float;

__device__ __forceinline__ us f2b(float f) {
  union { float f; uint32_t u; } v; v.f = f;
  uint32_t u = v.u;
  return (us)((u + 0x7fffu + ((u >> 16) & 1u)) >> 16);  // RNE
}

// pack two fp32 -> bf16x2 (round-half-up; P in [0,1], bias negligible)
__device__ __forceinline__ uint32_t pkbf(float a, float b) {
  union { float f; uint32_t u; } x, y; x.f = a; y.f = b;
  return ((x.u + 0x8000u) >> 16) | ((y.u + 0x8000u) & 0xFFFF0000u);
}

__device__ __forceinline__ void async16(void* lds, const void* g) {
  __builtin_amdgcn_global_load_lds(
      (__attribute__((address_space(1))) void*)(uintptr_t)g,
      (__attribute__((address_space(3))) void*)(uintptr_t)lds, 16, 0, 0);
}

// tanh-form GELU: 0.5x(1+tanh(k0(x+k1 x^3))) = x*sigmoid(2 k0 (x+k1 x^3))
// |err vs exact erf-gelu| < ~1e-3, below ff1's bf16 quantization.
__device__ __forceinline__ float gelu_f(float x) {
  const float z = -2.30211416f * x * (1.f + 0.044715f * x * x);  // -2*log2e*k0*(x+k1x^3)/x *x
  return x / (1.f + __builtin_amdgcn_exp2f(z));
}

// ---------------- transpose + cast: in [R][C] f32 -> out [C][R] bf16 ----------------
__global__ __launch_bounds__(256)
void transpose_cast(const float* __restrict__ in, us* __restrict__ out, int R, int C) {
  __shared__ float tile[32][33];
  const int bc = blockIdx.x * 32, br = blockIdx.y * 32;
  const int tx = threadIdx.x & 31, ty = threadIdx.x >> 5;
#pragma unroll
  for (int i = 0; i < 32; i += 8)
    tile[ty + i][tx] = in[(size_t)(br + ty + i) * C + bc + tx];
  __syncthreads();
#pragma unroll
  for (int i = 0; i < 32; i += 8)
    out[(size_t)(bc + ty + i) * R + br + tx] = f2b(tile[tx][ty + i]);
}

// ---------------- pack bq|bk|bv into one [3072] ----------------
__global__ void pack_bias(const float* __restrict__ bq, const float* __restrict__ bk,
                          const float* __restrict__ bv, float* __restrict__ o) {
  int i = blockIdx.x * 256 + threadIdx.x;
  o[i] = (i < 1024) ? bq[i] : (i < 2048 ? bk[i - 1024] : bv[i - 2048]);
}

// ---------------- LayerNorm: fp32 in -> bf16 out, one block per token ----------------
__global__ __launch_bounds__(256)
void ln_kernel(const float* __restrict__ x, const float* __restrict__ g,
               const float* __restrict__ be, us* __restrict__ out) {
  __shared__ float red[8];
  const int row = blockIdx.x, t = threadIdx.x;
  const float4 v = ((const float4*)(x + (size_t)row * EMB))[t];
  float s = v.x + v.y + v.z + v.w;
  float s2 = v.x * v.x + v.y * v.y + v.z * v.z + v.w * v.w;
#pragma unroll
  for (int o = 32; o; o >>= 1) { s += __shfl_down(s, o, 64); s2 += __shfl_down(s2, o, 64); }
  if ((t & 63) == 0) { red[(t >> 6) * 2] = s; red[(t >> 6) * 2 + 1] = s2; }
  __syncthreads();
  const float ts = red[0] + red[2] + red[4] + red[6];
  const float ts2 = red[1] + red[3] + red[5] + red[7];
  const float mu = ts * (1.f / 1024.f);
  const float rs = rsqrtf(ts2 * (1.f / 1024.f) - mu * mu + 1e-5f);
  const float4 gv = ((const float4*)g)[t];
  const float4 bv = ((const float4*)be)[t];
  ushort4 o4;
  o4.x = f2b((v.x - mu) * rs * gv.x + bv.x);
  o4.y = f2b((v.y - mu) * rs * gv.y + bv.y);
  o4.z = f2b((v.z - mu) * rs * gv.z + bv.z);
  o4.w = f2b((v.w - mu) * rs * gv.w + bv.w);
  ((ushort4*)(out + (size_t)row * EMB))[t] = o4;
}

// ---------------- GEMM 128x128: C[M][N] = epi(A[M][K] @ Bt[N][K]^T + bias) ----------------
// BK=64 via slice-major LDS ([s][128][32] per matrix, r3-proven free layout, no swizzle),
// 4 waves (2x2), 16x16x32 bf16 MFMA, global_load_lds staging, half the barriers of BK=32.
__global__ __launch_bounds__(256, 3)
void gemm_bt(const us* __restrict__ A, const us* __restrict__ Bt,
             const float* __restrict__ bias, const float* __restrict__ resid,
             float* __restrict__ outF, us* __restrict__ outB,
             int M, int N, int K, int gelu) {
  __shared__ us As[2 * 128 * 32];   // 16 KB, slice-major
  __shared__ us Bs[2 * 128 * 32];   // 16 KB
  const int tid = threadIdx.x;
  const int wave = tid >> 6, lane = tid & 63;
  const int wm = wave & 1, wn = wave >> 1;
  const int quad = lane >> 4, l15 = lane & 15;
  const int row0 = blockIdx.x * 128, col0 = blockIdx.y * 128;

  const f4 zf = {0.f, 0.f, 0.f, 0.f};
  f4 acc[4][4];
#pragma unroll
  for (int i = 0; i < 4; i++)
#pragma unroll
    for (int j = 0; j < 4; j++) acc[i][j] = zf;

  const int srow = lane >> 2;            // staged row within a 16-row op
  const int scol = (lane & 3) * 8;       // contiguous source col (us)
  const us* Ap = A + (size_t)(row0 + wave * 32 + srow) * K + scol;
  const us* Bp = Bt + (size_t)(col0 + wave * 32 + srow) * K + scol;
  us* asb = &As[(wave * 32) * 32];       // this wave's slice-0 dst
  us* bsb = &Bs[(wave * 32) * 32];
  const size_t rstep = (size_t)16 * K;

  for (int k0 = 0; k0 < K; k0 += 64) {
#pragma unroll
    for (int s = 0; s < 2; s++) {
      const int kc = k0 + s * 32;
      async16(asb + s * 4096, Ap + kc);
      async16(asb + s * 4096 + 512, Ap + rstep + kc);
      async16(bsb + s * 4096, Bp + kc);
      async16(bsb + s * 4096 + 512, Bp + rstep + kc);
    }
    __syncthreads();   // drains vmcnt for global_load_lds
#pragma unroll
    for (int s = 0; s < 2; s++) {
      b8 af[4], bf[4];
#pragma unroll
      for (int i = 0; i < 4; i++) {
        af[i] = *(const b8*)&As[s * 4096 + (wm * 64 + i * 16 + l15) * 32 + quad * 8];
        bf[i] = *(const b8*)&Bs[s * 4096 + (wn * 64 + i * 16 + l15) * 32 + quad * 8];
      }
#pragma unroll
      for (int i = 0; i < 4; i++)
#pragma unroll
        for (int j = 0; j < 4; j++)
          acc[i][j] = __builtin_amdgcn_mfma_f32_16x16x32_bf16(af[i], bf[j], acc[i][j], 0, 0, 0);
    }
    __syncthreads();
  }

  float bcol[4];
#pragma unroll
  for (int j = 0; j < 4; j++) bcol[j] = bias[col0 + wn * 64 + j * 16 + l15];
#pragma unroll
  for (int i = 0; i < 4; i++)
#pragma unroll
    for (int j = 0; j < 4; j++)
#pragma unroll
      for (int r = 0; r < 4; r++) {
        const int grow = row0 + wm * 64 + i * 16 + quad * 4 + r;
        const int gcol = col0 + wn * 64 + j * 16 + l15;
        float v = acc[i][j][r] + bcol[j];
        if (resid) v += resid[(size_t)grow * N + gcol];
        if (gelu) v = gelu_f(v);
        if (outF) outF[(size_t)grow * N + gcol] = v;
        if (outB) outB[(size_t)grow * N + gcol] = f2b(v);
      }
}

// ---------------- GEMM 64x128 (narrow-N variant, doubles grid for N=1024) ----------------
// 4 waves, each computes the full 64 rows x its 32-col strip. BK=64 slice-major, 24 KB LDS.
__global__ __launch_bounds__(256, 4)
void gemm_bt64(const us* __restrict__ A, const us* __restrict__ Bt,
               const float* __restrict__ bias, const float* __restrict__ resid,
               float* __restrict__ outF, us* __restrict__ outB,
               int M, int N, int K, int gelu) {
  __shared__ us As[2 * 64 * 32];    // 8 KB, slice-major
  __shared__ us Bs[2 * 128 * 32];   // 16 KB
  const int tid = threadIdx.x;
  const int wave = tid >> 6, lane = tid & 63;
  const int quad = lane >> 4, l15 = lane & 15;
  const int row0 = blockIdx.x * 64, col0 = blockIdx.y * 128;

  const f4 zf = {0.f, 0.f, 0.f, 0.f};
  f4 acc[4][2];
#pragma unroll
  for (int i = 0; i < 4; i++) { acc[i][0] = zf; acc[i][1] = zf; }

  const int srow = lane >> 2;
  const int scol = (lane & 3) * 8;
  const us* Ap = A + (size_t)(row0 + wave * 16 + srow) * K + scol;   // 1 op/slice: rows wave*16..+15
  const us* Bp = Bt + (size_t)(col0 + wave * 32 + srow) * K + scol;  // 2 ops/slice: rows wave*32..+31
  us* asb = &As[(wave * 16) * 32];
  us* bsb = &Bs[(wave * 32) * 32];
  const size_t rstep = (size_t)16 * K;

  for (int k0 = 0; k0 < K; k0 += 64) {
#pragma unroll
    for (int s = 0; s < 2; s++) {
      const int kc = k0 + s * 32;
      async16(asb + s * 2048, Ap + kc);
      async16(bsb + s * 4096, Bp + kc);
      async16(bsb + s * 4096 + 512, Bp + rstep + kc);
    }
    __syncthreads();
#pragma unroll
    for (int s = 0; s < 2; s++) {
      b8 af[4], bf[2];
#pragma unroll
      for (int i = 0; i < 4; i++)
        af[i] = *(const b8*)&As[s * 2048 + (i * 16 + l15) * 32 + quad * 8];
#pragma unroll
      for (int j = 0; j < 2; j++)
        bf[j] = *(const b8*)&Bs[s * 4096 + (wave * 32 + j * 16 + l15) * 32 + quad * 8];
#pragma unroll
      for (int i = 0; i < 4; i++)
#pragma unroll
        for (int j = 0; j < 2; j++)
          acc[i][j] = __builtin_amdgcn_mfma_f32_16x16x32_bf16(af[i], bf[j], acc[i][j], 0, 0, 0);
    }
    __syncthreads();
  }

  float bcol[2];
#pragma unroll
  for (int j = 0; j < 2; j++) bcol[j] = bias[col0 + wave * 32 + j * 16 + l15];
#pragma unroll
  for (int i = 0; i < 4; i++)
#pragma unroll
    for (int j = 0; j < 2; j++)
#pragma unroll
      for (int r = 0; r < 4; r++) {
        const int grow = row0 + i * 16 + quad * 4 + r;
        const int gcol = col0 + wave * 32 + j * 16 + l15;
        float v = acc[i][j][r] + bcol[j];
        if (resid) v += resid[(size_t)grow * N + gcol];
        if (gelu) v = gelu_f(v);
        if (outF) outF[(size_t)grow * N + gcol] = v;
        if (outB) outB[(size_t)grow * N + gcol] = f2b(v);
      }
}

// ---------------- causal flash attention, operand-swapped, reg-blocked ----------------
// qkv: [NTOK][3072] bf16 (q|k|v). y: [NTOK][1024] bf16.
// S^T = K·Q^T (P stays in registers in A-layout for O = P·V).
// 256 threads = 4 waves; each wave owns 32 q-rows (two 16-q groups) of a 128-q tile.
// K in LDS with XOR column swizzle (conflict-free b128 reads, async-DMA staged).
// V^T in LDS stride 132 us, b64 reads + register zero-pad (conflict-free).
__global__ __launch_bounds__(256, 3)
void attn(const us* __restrict__ qkv, us* __restrict__ y) {
  // magic-square qt mapping: each CU-coset of blocks gets equal total work
  static const signed char QTM[16] = {15,14,13,12, 10,11,8,9, 5,4,7,6, 0,1,2,3};
  const int bx = blockIdx.x;
  const int bh = bx & 63;
  const int qt = QTM[(bx >> 6) & 15];
  const int bb = bh >> 4, h = bh & 15;
  const int tid = threadIdx.x;
  const int wave = tid >> 6, lane = tid & 63;
  const int quad = lane >> 4, l15 = lane & 15;

  __shared__ us Ks[128 * 64];   // phys us off = row*64 + ((col8 ^ (row&7))<<3)
  __shared__ us Vt[64 * 132];   // V^T[d][key], us off = d*132 + key

  const size_t base = (size_t)bb * SEQ * 3072;
  const int q0 = qt * 128;

  // Q B-fragments for two 16-q groups (rows wave*32 + qg*16 + l15)
  b8 bqf[2][2];
#pragma unroll
  for (int qg = 0; qg < 2; qg++) {
    const us* qp = qkv + base + (size_t)(q0 + wave * 32 + qg * 16 + l15) * 3072 + h * 64 + quad * 8;
    bqf[qg][0] = *(const b8*)qp;
    bqf[qg][1] = *(const b8*)(qp + 32);
  }

  const f4 zf = {0.f, 0.f, 0.f, 0.f};
  f4 o[2][4];                       // [qg][dg]: O[q=quad*4+r][d=dg*16+l15]
  float mrow[2], lrow[2];
#pragma unroll
  for (int qg = 0; qg < 2; qg++) {
    mrow[qg] = -3.0e38f; lrow[qg] = 0.f;
#pragma unroll
    for (int dg = 0; dg < 4; dg++) o[qg][dg] = zf;
  }

  // K staging: wave stages rows wave*32..+31 in 4 DMA ops of 8 rows.
  const int klr = lane >> 3, klc = lane & 7;
  const us* kgbase = qkv + base + (size_t)(wave * 32 + klr) * 3072 + 1024 + h * 64 + ((klc ^ klr) << 3);
  // V staging: thread handles key pair (2*lane, 2*lane+1), d-octets wave*8 and 32+wave*8.
  const us* vgbase = qkv + base + (size_t)(2 * lane) * 3072 + 2048 + h * 64 + wave * 8;

  const float sm_scale = 0.125f * 1.44269504088896340736f;  // 1/sqrt(64) * log2(e)

  for (int kt = 0; kt <= qt; kt++) {
    const size_t koff = (size_t)kt * 128 * 3072;
    // --- stage K (async DMA, XOR-swizzled source) ---
#pragma unroll
    for (int op = 0; op < 4; op++)
      async16(&Ks[(wave * 32 + op * 8) * 64], kgbase + koff + (size_t)op * 8 * 3072);
    // --- stage V^T (manual transpose, conflict-free packed writes) ---
    {
      union { float4 f; us u[8]; } v0, v1, v2, v3;
      v0.f = *(const float4*)(vgbase + koff);
      v1.f = *(const float4*)(vgbase + koff + 3072);
      v2.f = *(const float4*)(vgbase + koff + 32);
      v3.f = *(const float4*)(vgbase + koff + 3072 + 32);
#pragma unroll
      for (int j = 0; j < 8; j++) {
        *(uint32_t*)&Vt[(wave * 8 + j) * 132 + 2 * lane] =
            (uint32_t)v0.u[j] | ((uint32_t)v1.u[j] << 16);
        *(uint32_t*)&Vt[(32 + wave * 8 + j) * 132 + 2 * lane] =
            (uint32_t)v2.u[j] | ((uint32_t)v3.u[j] << 16);
      }
    }
    __syncthreads();

    // --- S^T = K·Q^T : sacc[qg][c] holds S^T[key=c*16+quad*4+r][q=l15] ---
    f4 sacc[2][8];
#pragma unroll
    for (int c = 0; c < 8; c++) {
      const int krow = (c * 16 + l15) * 64;
      const int sw = l15 & 7;
      const b8 ak0 = *(const b8*)&Ks[krow + ((quad ^ sw) << 3)];
      const b8 ak1 = *(const b8*)&Ks[krow + (((quad ^ 4) ^ sw) << 3)];
#pragma unroll
      for (int qg = 0; qg < 2; qg++) {
        f4 s = __builtin_amdgcn_mfma_f32_16x16x32_bf16(ak0, bqf[qg][0], zf, 0, 0, 0);
        sacc[qg][c] = __builtin_amdgcn_mfma_f32_16x16x32_bf16(ak1, bqf[qg][1], s, 0, 0, 0);
      }
    }

    // --- softmax per q-group; pack P into A-fragment halves ---
    uint32_t pf[2][16];
    float alpha[2];
#pragma unroll
    for (int qg = 0; qg < 2; qg++) {
      const int q_in = wave * 32 + qg * 16 + l15;
#pragma unroll
      for (int c = 0; c < 8; c++)
#pragma unroll
        for (int r = 0; r < 4; r++) {
          float v = sacc[qg][c][r] * sm_scale;
          if (kt == qt && (c * 16 + quad * 4 + r) > q_in) v = -3.0e38f;
          sacc[qg][c][r] = v;
        }
      float mx = sacc[qg][0][0];
#pragma unroll
      for (int c = 0; c < 8; c++)
#pragma unroll
        for (int r = 0; r < 4; r++) mx = fmaxf(mx, sacc[qg][c][r]);
      mx = fmaxf(mx, __shfl_xor(mx, 16, 64));
      mx = fmaxf(mx, __shfl_xor(mx, 32, 64));
      const float mnew = fmaxf(mrow[qg], mx);
      alpha[qg] = __builtin_amdgcn_exp2f(mrow[qg] - mnew);
      mrow[qg] = mnew;
      float rs = 0.f;
#pragma unroll
      for (int c = 0; c < 8; c++) {
        const float p0 = __builtin_amdgcn_exp2f(sacc[qg][c][0] - mnew);
        const float p1 = __builtin_amdgcn_exp2f(sacc[qg][c][1] - mnew);
        const float p2 = __builtin_amdgcn_exp2f(sacc[qg][c][2] - mnew);
        const float p3 = __builtin_amdgcn_exp2f(sacc[qg][c][3] - mnew);
        rs += (p0 + p1) + (p2 + p3);
        pf[qg][c * 2] = pkbf(p0, p1);
        pf[qg][c * 2 + 1] = pkbf(p2, p3);
      }
      rs += __shfl_xor(rs, 16, 64);
      rs += __shfl_xor(rs, 32, 64);
      lrow[qg] = lrow[qg] * alpha[qg] + rs;
      // rescale O rows (row q' = quad*4+r needs alpha from lane l15=q')
#pragma unroll
      for (int r = 0; r < 4; r++) {
        const float ar = __shfl(alpha[qg], quad * 4 + r, 64);
#pragma unroll
        for (int dg = 0; dg < 4; dg++) o[qg][dg][r] *= ar;
      }
    }

    // --- O += P·V : V b64 reads shared across q-groups; zero-padded halves ---
#pragma unroll
    for (int c = 0; c < 8; c++) {
      union { uint32_t w[4]; b8 v; } af0, af1;
      af0.w[0] = pf[0][c * 2]; af0.w[1] = pf[0][c * 2 + 1]; af0.w[2] = 0u; af0.w[3] = 0u;
      af1.w[0] = pf[1][c * 2]; af1.w[1] = pf[1][c * 2 + 1]; af1.w[2] = 0u; af1.w[3] = 0u;
#pragma unroll
      for (int dg = 0; dg < 4; dg++) {
        const uint2 vd = *(const uint2*)&Vt[(dg * 16 + l15) * 132 + c * 16 + quad * 4];
        union { uint32_t w[4]; b8 v; } vb;
        vb.w[0] = vd.x; vb.w[1] = vd.y; vb.w[2] = 0u; vb.w[3] = 0u;
        o[0][dg] = __builtin_amdgcn_mfma_f32_16x16x32_bf16(af0.v, vb.v, o[0][dg], 0, 0, 0);
        o[1][dg] = __builtin_amdgcn_mfma_f32_16x16x32_bf16(af1.v, vb.v, o[1][dg], 0, 0, 0);
      }
    }
    __syncthreads();   // before next tile overwrites Ks/Vt
  }

#pragma unroll
  for (int qg = 0; qg < 2; qg++) {
    float lr[4];
#pragma unroll
    for (int r = 0; r < 4; r++) lr[r] = __shfl(lrow[qg], quad * 4 + r, 64);
#pragma unroll
    for (int dg = 0; dg < 4; dg++)
#pragma unroll
      for (int r = 0; r < 4; r++) {
        const int gq = q0 + wave * 32 + qg * 16 + quad * 4 + r;
        y[(size_t)(bb * SEQ + gq) * EMB + h * 64 + dg * 16 + l15] = f2b(o[qg][dg][r] / lr[r]);
      }
  }
}

extern "C" void kernel_launch(void* const* d_in, const int* in_sizes, int n_in,
                              void* d_out, int out_size, void* d_ws, size_t ws_size,
                              hipStream_t stream) {
  const float* x = (const float*)d_in[0];
  const float* Wq = (const float*)d_in[1];
  const float* bq = (const float*)d_in[2];
  const float* Wk = (const float*)d_in[3];
  const float* bk = (const float*)d_in[4];
  const float* Wv = (const float*)d_in[5];
  const float* bv = (const float*)d_in[6];
  const float* Wo = (const float*)d_in[7];
  const float* bo = (const float*)d_in[8];
  const float* g1 = (const float*)d_in[9];
  const float* be1 = (const float*)d_in[10];
  const float* g2 = (const float*)d_in[11];
  const float* be2 = (const float*)d_in[12];
  const float* W1 = (const float*)d_in[13];
  const float* b1 = (const float*)d_in[14];
  const float* W2 = (const float*)d_in[15];
  const float* b2 = (const float*)d_in[16];
  float* out = (float*)d_out;

  char* ws = (char*)d_ws;
  const size_t MB = 1024ull * 1024ull;
  us* WqkvT = (us*)(ws + 0);          // [3072][1024] bf16
  us* WoT   = (us*)(ws + 6 * MB);     // [1024][1024]
  us* W1T   = (us*)(ws + 8 * MB);     // [4096][1024]
  us* W2T   = (us*)(ws + 16 * MB);    // [1024][4096]
  us* hbuf  = (us*)(ws + 24 * MB);    // [8192][1024] bf16 (LN1 out)
  us* qkvb  = (us*)(ws + 40 * MB);    // [8192][3072] bf16
  us* ybuf  = (us*)(ws + 88 * MB);    // [8192][1024] bf16
  float* x1 = (float*)(ws + 104 * MB);// [8192][1024] f32
  us* h2    = (us*)(ws + 136 * MB);   // [8192][1024] bf16
  us* ff1   = (us*)(ws + 24 * MB);    // [8192][4096] bf16 (reuses h/qkv region)
  float* bqkv = (float*)(ws + 152 * MB); // [3072] f32

  transpose_cast<<<dim3(32, 32), 256, 0, stream>>>(Wq, WqkvT, 1024, 1024);
  transpose_cast<<<dim3(32, 32), 256, 0, stream>>>(Wk, WqkvT + 1024 * 1024, 1024, 1024);
  transpose_cast<<<dim3(32, 32), 256, 0, stream>>>(Wv, WqkvT + 2 * 1024 * 1024, 1024, 1024);
  transpose_cast<<<dim3(32, 32), 256, 0, stream>>>(Wo, WoT, 1024, 1024);
  transpose_cast<<<dim3(128, 32), 256, 0, stream>>>(W1, W1T, 1024, 4096);
  transpose_cast<<<dim3(32, 128), 256, 0, stream>>>(W2, W2T, 4096, 1024);
  pack_bias<<<12, 256, 0, stream>>>(bq, bk, bv, bqkv);

  ln_kernel<<<NTOK, 256, 0, stream>>>(x, g1, be1, hbuf);
  gemm_bt<<<dim3(64, 24), 256, 0, stream>>>(hbuf, WqkvT, bqkv, nullptr, nullptr, qkvb,
                                            NTOK, 3072, 1024, 0);
  attn<<<1024, 256, 0, stream>>>(qkvb, ybuf);
  gemm_bt64<<<dim3(128, 8), 256, 0, stream>>>(ybuf, WoT, bo, x, x1, nullptr,
                                              NTOK, 1024, 1024, 0);
  ln_kernel<<<NTOK, 256, 0, stream>>>(x1, g2, be2, h2);
  gemm_bt<<<dim3(64, 32), 256, 0, stream>>>(h2, W1T, b1, nullptr, nullptr, ff1,
                                            NTOK, 4096, 1024, 1);
  gemm_bt64<<<dim3(128, 8), 256, 0, stream>>>(ff1, W2T, b2, x1, out, nullptr,
                                              NTOK, 1024, 4096, 0);
}